// Round 1
// baseline (335.207 us; speedup 1.0000x reference)
//
#include <hip/hip_runtime.h>
#include <cstddef>

#define B_ 64
#define T_ 1000
#define F_ 512
#define H_ 8
#define KD_ 32
#define HK_ 256   // H_*KD_

// ---------------- K1: qh[h,k] = sum_f q[f]*Wq[f,h,k] + bq[h,k] ----------------
__global__ __launch_bounds__(64) void k_qh(const float* __restrict__ q,
                                           const float* __restrict__ Wq,
                                           const float* __restrict__ bq,
                                           float* __restrict__ qh) {
    int hk = blockIdx.x;           // 0..255
    int lane = threadIdx.x;        // 0..63
    float s = 0.f;
    for (int f = lane; f < F_; f += 64) s += q[f] * Wq[(size_t)f * HK_ + hk];
    #pragma unroll
    for (int off = 32; off; off >>= 1) s += __shfl_down(s, off);
    if (lane == 0) qh[hk] = s + bq[hk];
}

// ---------------- K2: wk[f,h] = sum_k qh[h,k]*Wk[f,h,k]; ck[h] = qh[h,:].bk[h,:] ----------------
__global__ __launch_bounds__(256) void k_wk(const float* __restrict__ qh,
                                            const float* __restrict__ Wk,
                                            const float* __restrict__ bk,
                                            float* __restrict__ wk,
                                            float* __restrict__ ck) {
    int f = blockIdx.x;            // 0..511
    int tid = threadIdx.x;         // tid = h*32+k
    __shared__ float red[256];
    red[tid] = qh[tid] * Wk[(size_t)f * HK_ + tid];
    __syncthreads();
    #pragma unroll
    for (int off = 16; off; off >>= 1) {
        if ((tid & 31) < off) red[tid] += red[tid + off];
        __syncthreads();
    }
    if ((tid & 31) == 0) wk[f * H_ + (tid >> 5)] = red[tid];
    if (f == 0 && tid < H_) {
        float c = 0.f;
        for (int k = 0; k < KD_; k++) c += qh[tid * KD_ + k] * bk[tid * KD_ + k];
        ck[tid] = c;
    }
}

// ---------------- K3: scores[b,h,t] = scale*(x[b,t,:].wk[:,h] + ck[h]) ----------------
// One wave per (b,t) row. Each lane owns f = lane*8 .. lane*8+7; wk_eff hoisted to regs.
__global__ __launch_bounds__(256) void k_scores(const float* __restrict__ x,
                                                const float* __restrict__ wk,
                                                const float* __restrict__ ck,
                                                float* __restrict__ scores) {
    int gtid = blockIdx.x * blockDim.x + threadIdx.x;
    int wid = gtid >> 6;
    int lane = threadIdx.x & 63;
    int nw = (gridDim.x * blockDim.x) >> 6;
    int f0 = lane * 8;
    float wreg[8][8];   // [i][h]
    #pragma unroll
    for (int i = 0; i < 8; i++)
        #pragma unroll
        for (int h = 0; h < H_; h++) wreg[i][h] = wk[(f0 + i) * H_ + h];
    float ckr[8];
    #pragma unroll
    for (int h = 0; h < H_; h++) ckr[h] = ck[h];
    const float scale = 0.17677669529663687f;  // 1/sqrt(32)

    for (int row = wid; row < B_ * T_; row += nw) {
        const float4* xr = (const float4*)(x + (size_t)row * F_ + f0);
        float4 a = xr[0], bb = xr[1];
        float xv[8] = {a.x, a.y, a.z, a.w, bb.x, bb.y, bb.z, bb.w};
        float acc[8];
        #pragma unroll
        for (int h = 0; h < H_; h++) acc[h] = 0.f;
        #pragma unroll
        for (int i = 0; i < 8; i++)
            #pragma unroll
            for (int h = 0; h < H_; h++) acc[h] += xv[i] * wreg[i][h];
        #pragma unroll
        for (int h = 0; h < H_; h++)
            #pragma unroll
            for (int off = 32; off; off >>= 1) acc[h] += __shfl_xor(acc[h], off);
        if (lane < H_) {
            // static-index select (avoid runtime array index -> scratch)
            float v = acc[0];
            #pragma unroll
            for (int h = 1; h < H_; h++) v = (lane == h) ? acc[h] : v;
            int b = row / T_, t = row - b * T_;
            scores[((size_t)b * H_ + lane) * T_ + t] = (v + ckr[lane]) * scale;
        }
    }
}

// ---------------- K4: softmax over t per (b,h) row, in place ----------------
__global__ __launch_bounds__(256) void k_softmax(float* __restrict__ scores) {
    int row = blockIdx.x;   // 0..511
    int tid = threadIdx.x;
    float* s = scores + (size_t)row * T_;
    __shared__ float red[256];
    float m = -1e30f;
    for (int t = tid; t < T_; t += 256) m = fmaxf(m, s[t]);
    red[tid] = m; __syncthreads();
    #pragma unroll
    for (int off = 128; off; off >>= 1) {
        if (tid < off) red[tid] = fmaxf(red[tid], red[tid + off]);
        __syncthreads();
    }
    m = red[0]; __syncthreads();
    float sum = 0.f;
    for (int t = tid; t < T_; t += 256) { float e = __expf(s[t] - m); s[t] = e; sum += e; }
    red[tid] = sum; __syncthreads();
    #pragma unroll
    for (int off = 128; off; off >>= 1) {
        if (tid < off) red[tid] += red[tid + off];
        __syncthreads();
    }
    float inv = 1.0f / red[0];
    for (int t = tid; t < T_; t += 256) s[t] *= inv;
}

// ---------------- K5: xp[b,h,f] = sum_t attn[b,h,t]*x[b,t,f]  (atomic over t-chunks) ----------------
__global__ __launch_bounds__(256) void k_xp(const float* __restrict__ x,
                                            const float* __restrict__ attn,
                                            float* __restrict__ xp) {
    int bid = blockIdx.x;                 // b*8 + fc*4 + tc
    int tc = bid & 3;
    int fc = (bid >> 2) & 1;
    int b  = bid >> 3;
    int tid = threadIdx.x;
    int t0 = tc * 250, f0 = fc * 256;
    __shared__ float at[H_][256];
    for (int i = tid; i < H_ * 250; i += 256) {
        int h = i / 250, t = i - h * 250;
        at[h][t] = attn[((size_t)b * H_ + h) * T_ + t0 + t];
    }
    __syncthreads();
    float acc[H_] = {0.f,0.f,0.f,0.f,0.f,0.f,0.f,0.f};
    const float* xb = x + ((size_t)b * T_ + t0) * F_ + f0 + tid;
    for (int t = 0; t < 250; t++) {
        float xv = xb[(size_t)t * F_];
        #pragma unroll
        for (int h = 0; h < H_; h++) acc[h] += at[h][t] * xv;
    }
    #pragma unroll
    for (int h = 0; h < H_; h++)
        atomicAdd(&xp[((size_t)b * H_ + h) * F_ + f0 + tid], acc[h]);
}

// ---------------- K6: ctx -> pooled -> Wd -> LayerNorm, one block per b ----------------
__global__ __launch_bounds__(256) void k_final(const float* __restrict__ xp,
                                               const float* __restrict__ Wv,
                                               const float* __restrict__ bv,
                                               const float* __restrict__ Wo,
                                               const float* __restrict__ bo,
                                               const float* __restrict__ Wd,
                                               const float* __restrict__ gamma,
                                               const float* __restrict__ beta,
                                               float* __restrict__ out) {
    int b = blockIdx.x;
    int tid = threadIdx.x;
    __shared__ float xps[H_ * F_];   // 16 KB
    __shared__ float ctx[HK_];
    __shared__ float pooled[F_];
    __shared__ float red[256];
    for (int i = tid; i < H_ * F_; i += 256) xps[i] = xp[(size_t)b * H_ * F_ + i];
    __syncthreads();
    // ctx[h,k] = sum_f xps[h][f] * Wv[f,h,k] + bv[h,k]
    {
        int h = tid >> 5;
        float s = 0.f;
        for (int f = 0; f < F_; f++) s += xps[h * F_ + f] * Wv[(size_t)f * HK_ + tid];
        ctx[tid] = s + bv[tid];
    }
    __syncthreads();
    // pooled[f] = sum_hk ctx[hk]*Wo[hk,f] + bo[f]
    #pragma unroll
    for (int j = 0; j < 2; j++) {
        int f = tid + j * 256;
        float s = 0.f;
        for (int hk = 0; hk < HK_; hk++) s += ctx[hk] * Wo[(size_t)hk * F_ + f];
        pooled[f] = s + bo[f];
    }
    __syncthreads();
    // o[f] = sum_g pooled[g]*Wd[g,f]
    float o[2];
    #pragma unroll
    for (int j = 0; j < 2; j++) {
        int f = tid + j * 256;
        float s = 0.f;
        for (int g = 0; g < F_; g++) s += pooled[g] * Wd[(size_t)g * F_ + f];
        o[j] = s;
    }
    // LayerNorm over 512
    red[tid] = o[0] + o[1]; __syncthreads();
    #pragma unroll
    for (int off = 128; off; off >>= 1) { if (tid < off) red[tid] += red[tid + off]; __syncthreads(); }
    float mu = red[0] * (1.0f / F_); __syncthreads();
    float d0 = o[0] - mu, d1 = o[1] - mu;
    red[tid] = d0 * d0 + d1 * d1; __syncthreads();
    #pragma unroll
    for (int off = 128; off; off >>= 1) { if (tid < off) red[tid] += red[tid + off]; __syncthreads(); }
    float rstd = rsqrtf(red[0] * (1.0f / F_) + 1e-6f);
    #pragma unroll
    for (int j = 0; j < 2; j++) {
        int f = tid + j * 256;
        out[(size_t)b * F_ + f] = (o[j] - mu) * rstd * gamma[f] + beta[f];
    }
}

extern "C" void kernel_launch(void* const* d_in, const int* in_sizes, int n_in,
                              void* d_out, int out_size, void* d_ws, size_t ws_size,
                              hipStream_t stream) {
    const float* x     = (const float*)d_in[0];
    const float* q     = (const float*)d_in[1];
    const float* Wq    = (const float*)d_in[2];
    const float* bq    = (const float*)d_in[3];
    const float* Wk    = (const float*)d_in[4];
    const float* bk    = (const float*)d_in[5];
    const float* Wv    = (const float*)d_in[6];
    const float* bv    = (const float*)d_in[7];
    const float* Wo    = (const float*)d_in[8];
    const float* bo    = (const float*)d_in[9];
    const float* Wd    = (const float*)d_in[10];
    const float* gamma = (const float*)d_in[11];
    const float* beta  = (const float*)d_in[12];
    float* out = (float*)d_out;

    char* ws = (char*)d_ws;
    float* qh     = (float*)(ws + 0);            // 256 f
    float* wk     = (float*)(ws + 4096);         // 4096 f
    float* ck     = (float*)(ws + 20480);        // 8 f
    float* scores = (float*)(ws + 24576);        // 512000 f (2 MB)
    float* xp     = (float*)(ws + 2097152);      // 262144 f (1 MB)

    k_qh<<<HK_, 64, 0, stream>>>(q, Wq, bq, qh);
    k_wk<<<F_, 256, 0, stream>>>(qh, Wk, bk, wk, ck);
    k_scores<<<1024, 256, 0, stream>>>(x, wk, ck, scores);
    k_softmax<<<B_ * H_, 256, 0, stream>>>(scores);
    hipMemsetAsync(xp, 0, (size_t)B_ * H_ * F_ * sizeof(float), stream);
    k_xp<<<B_ * 8, 256, 0, stream>>>(x, scores, xp);
    k_final<<<B_, 256, 0, stream>>>(xp, Wv, bv, Wo, bo, Wd, gamma, beta, out);
}

// Round 2
// 301.553 us; speedup vs baseline: 1.1116x; 1.1116x over previous
//
#include <hip/hip_runtime.h>
#include <cstddef>

#define B_ 64
#define T_ 1000
#define F_ 512
#define H_ 8
#define KD_ 32
#define HK_ 256   // H_*KD_

// ---------------- K1: qh[h,k] = sum_f q[f]*Wq[f,h,k] + bq[h,k] ----------------
__global__ __launch_bounds__(64) void k_qh(const float* __restrict__ q,
                                           const float* __restrict__ Wq,
                                           const float* __restrict__ bq,
                                           float* __restrict__ qh) {
    int hk = blockIdx.x;           // 0..255
    int lane = threadIdx.x;        // 0..63
    float s = 0.f;
    for (int f = lane; f < F_; f += 64) s += q[f] * Wq[(size_t)f * HK_ + hk];
    #pragma unroll
    for (int off = 32; off; off >>= 1) s += __shfl_down(s, off);
    if (lane == 0) qh[hk] = s + bq[hk];
}

// ---------------- K2: wk[f,h] = sum_k qh[h,k]*Wk[f,h,k]; ck[h] = qh[h,:].bk[h,:] ----------------
__global__ __launch_bounds__(256) void k_wk(const float* __restrict__ qh,
                                            const float* __restrict__ Wk,
                                            const float* __restrict__ bk,
                                            float* __restrict__ wk,
                                            float* __restrict__ ck) {
    int f = blockIdx.x;            // 0..511
    int tid = threadIdx.x;         // tid = h*32+k
    __shared__ float red[256];
    red[tid] = qh[tid] * Wk[(size_t)f * HK_ + tid];
    __syncthreads();
    #pragma unroll
    for (int off = 16; off; off >>= 1) {
        if ((tid & 31) < off) red[tid] += red[tid + off];
        __syncthreads();
    }
    if ((tid & 31) == 0) wk[f * H_ + (tid >> 5)] = red[tid];
    if (f == 0 && tid < H_) {
        float c = 0.f;
        for (int k = 0; k < KD_; k++) c += qh[tid * KD_ + k] * bk[tid * KD_ + k];
        ck[tid] = c;
    }
}

// ---------------- K3: scores[b,h,t] = scale*(x[b,t,:].wk[:,h] + ck[h]) ----------------
__global__ __launch_bounds__(256) void k_scores(const float* __restrict__ x,
                                                const float* __restrict__ wk,
                                                const float* __restrict__ ck,
                                                float* __restrict__ scores) {
    int gtid = blockIdx.x * blockDim.x + threadIdx.x;
    int wid = gtid >> 6;
    int lane = threadIdx.x & 63;
    int nw = (gridDim.x * blockDim.x) >> 6;
    int f0 = lane * 8;
    float wreg[8][8];   // [i][h]
    #pragma unroll
    for (int i = 0; i < 8; i++)
        #pragma unroll
        for (int h = 0; h < H_; h++) wreg[i][h] = wk[(f0 + i) * H_ + h];
    float ckr[8];
    #pragma unroll
    for (int h = 0; h < H_; h++) ckr[h] = ck[h];
    const float scale = 0.17677669529663687f;  // 1/sqrt(32)

    for (int row = wid; row < B_ * T_; row += nw) {
        const float4* xr = (const float4*)(x + (size_t)row * F_ + f0);
        float4 a = xr[0], bb = xr[1];
        float xv[8] = {a.x, a.y, a.z, a.w, bb.x, bb.y, bb.z, bb.w};
        float acc[8];
        #pragma unroll
        for (int h = 0; h < H_; h++) acc[h] = 0.f;
        #pragma unroll
        for (int i = 0; i < 8; i++)
            #pragma unroll
            for (int h = 0; h < H_; h++) acc[h] += xv[i] * wreg[i][h];
        #pragma unroll
        for (int h = 0; h < H_; h++)
            #pragma unroll
            for (int off = 32; off; off >>= 1) acc[h] += __shfl_xor(acc[h], off);
        if (lane < H_) {
            float v = acc[0];
            #pragma unroll
            for (int h = 1; h < H_; h++) v = (lane == h) ? acc[h] : v;
            int b = row / T_, t = row - b * T_;
            scores[((size_t)b * H_ + lane) * T_ + t] = (v + ckr[lane]) * scale;
        }
    }
}

// ---------------- K4: softmax over t per (b,h) row, in place ----------------
__global__ __launch_bounds__(256) void k_softmax(float* __restrict__ scores) {
    int row = blockIdx.x;   // 0..511
    int tid = threadIdx.x;
    float* s = scores + (size_t)row * T_;
    __shared__ float red[256];
    float m = -1e30f;
    for (int t = tid; t < T_; t += 256) m = fmaxf(m, s[t]);
    red[tid] = m; __syncthreads();
    #pragma unroll
    for (int off = 128; off; off >>= 1) {
        if (tid < off) red[tid] = fmaxf(red[tid], red[tid + off]);
        __syncthreads();
    }
    m = red[0]; __syncthreads();
    float sum = 0.f;
    for (int t = tid; t < T_; t += 256) { float e = __expf(s[t] - m); s[t] = e; sum += e; }
    red[tid] = sum; __syncthreads();
    #pragma unroll
    for (int off = 128; off; off >>= 1) {
        if (tid < off) red[tid] += red[tid + off];
        __syncthreads();
    }
    float inv = 1.0f / red[0];
    for (int t = tid; t < T_; t += 256) s[t] *= inv;
}

// ---------------- K5: xp_part[p][b][h][f] = sum_{t in chunk p} attn[b,h,t]*x[b,t,f] ----------------
// 8 t-chunks of 125; float2 loads; no atomics (partials summed in k_tail).
__global__ __launch_bounds__(256) void k_xp(const float* __restrict__ x,
                                            const float* __restrict__ attn,
                                            float* __restrict__ xp_part) {
    int bid = blockIdx.x;          // b*8 + tc
    int tc = bid & 7;
    int b  = bid >> 3;
    int tid = threadIdx.x;         // f2 index: f = tid*2
    int t0 = tc * 125;
    __shared__ float at[H_][128];
    for (int i = tid; i < H_ * 128; i += 256) {
        int h = i >> 7, t = i & 127;
        at[h][t] = (t < 125) ? attn[((size_t)b * H_ + h) * T_ + t0 + t] : 0.f;
    }
    __syncthreads();
    float acc[H_][2];
    #pragma unroll
    for (int h = 0; h < H_; h++) { acc[h][0] = 0.f; acc[h][1] = 0.f; }
    const float2* xb = (const float2*)(x + ((size_t)b * T_ + t0) * F_) + tid;
    for (int t = 0; t < 125; t++) {
        float2 xv = xb[(size_t)t * 256];
        #pragma unroll
        for (int h = 0; h < H_; h++) {
            float a = at[h][t];
            acc[h][0] += a * xv.x;
            acc[h][1] += a * xv.y;
        }
    }
    float2* dst = (float2*)(xp_part + ((size_t)(tc * B_ + b) * H_) * F_);
    #pragma unroll
    for (int h = 0; h < H_; h++)
        dst[h * (F_ / 2) + tid] = make_float2(acc[h][0], acc[h][1]);
}

// ---------------- K6: sum partials -> ctx -> pooled -> Wd -> LayerNorm, one block per b ----------------
__global__ __launch_bounds__(512) void k_tail(const float* __restrict__ xp_part,
                                              const float* __restrict__ Wv,
                                              const float* __restrict__ bv,
                                              const float* __restrict__ Wo,
                                              const float* __restrict__ bo,
                                              const float* __restrict__ Wd,
                                              const float* __restrict__ gamma,
                                              const float* __restrict__ beta,
                                              float* __restrict__ out) {
    int b = blockIdx.x;
    int tid = threadIdx.x;
    __shared__ float xs[H_ * F_];     // 16 KB, [h][f]
    __shared__ float ctx_s[HK_];
    __shared__ float pooled_s[F_];
    __shared__ float red[512];
    __shared__ float stat[2];

    for (int i = tid; i < H_ * F_; i += 512) {
        float s = 0.f;
        #pragma unroll
        for (int p = 0; p < 8; p++)
            s += xp_part[(size_t)(p * B_ + b) * (H_ * F_) + i];
        xs[i] = s;
    }
    __syncthreads();

    // ctx[hk] = sum_f xs[h][f]*Wv[f*256+hk] + bv[hk]; split f over 2 halves
    {
        int hk = tid & 255;
        int half = tid >> 8;
        int h = hk >> 5;
        float s = 0.f;
        int fb = half * 256;
        for (int j = 0; j < 256; j++) {
            int f = fb + j;
            s += xs[h * F_ + f] * Wv[(size_t)f * HK_ + hk];
        }
        red[tid] = s;
        __syncthreads();
        if (tid < 256) ctx_s[tid] = red[tid] + red[tid + 256] + bv[tid];
    }
    __syncthreads();

    // pooled[f] = sum_hk ctx[hk]*Wo[hk*512+f] + bo[f]
    {
        float s = 0.f;
        for (int hk = 0; hk < HK_; hk++) s += ctx_s[hk] * Wo[(size_t)hk * F_ + tid];
        pooled_s[tid] = s + bo[tid];
    }
    __syncthreads();

    // o[f] = sum_g pooled[g]*Wd[g*512+f]
    float o = 0.f;
    for (int g = 0; g < F_; g++) o += pooled_s[g] * Wd[(size_t)g * F_ + tid];

    // LayerNorm over 512 (sum + sumsq wave reduce -> block reduce)
    {
        float v1 = o, v2 = o * o;
        #pragma unroll
        for (int off = 32; off; off >>= 1) {
            v1 += __shfl_down(v1, off);
            v2 += __shfl_down(v2, off);
        }
        int lane = tid & 63, wid = tid >> 6;
        if (lane == 0) { red[wid] = v1; red[8 + wid] = v2; }
        __syncthreads();
        if (tid == 0) {
            float s1 = 0.f, s2 = 0.f;
            #pragma unroll
            for (int w = 0; w < 8; w++) { s1 += red[w]; s2 += red[8 + w]; }
            float mu = s1 * (1.0f / F_);
            float var = s2 * (1.0f / F_) - mu * mu;
            stat[0] = mu;
            stat[1] = rsqrtf(var + 1e-6f);
        }
        __syncthreads();
    }
    float mu = stat[0], rstd = stat[1];
    out[(size_t)b * F_ + tid] = (o - mu) * rstd * gamma[tid] + beta[tid];
}

extern "C" void kernel_launch(void* const* d_in, const int* in_sizes, int n_in,
                              void* d_out, int out_size, void* d_ws, size_t ws_size,
                              hipStream_t stream) {
    const float* x     = (const float*)d_in[0];
    const float* q     = (const float*)d_in[1];
    const float* Wq    = (const float*)d_in[2];
    const float* bq    = (const float*)d_in[3];
    const float* Wk    = (const float*)d_in[4];
    const float* bk    = (const float*)d_in[5];
    const float* Wv    = (const float*)d_in[6];
    const float* bv    = (const float*)d_in[7];
    const float* Wo    = (const float*)d_in[8];
    const float* bo    = (const float*)d_in[9];
    const float* Wd    = (const float*)d_in[10];
    const float* gamma = (const float*)d_in[11];
    const float* beta  = (const float*)d_in[12];
    float* out = (float*)d_out;

    char* ws = (char*)d_ws;
    float* qh      = (float*)(ws + 0);            // 256 f
    float* wk      = (float*)(ws + 4096);         // 4096 f
    float* ck      = (float*)(ws + 20480);        // 8 f
    float* scores  = (float*)(ws + 24576);        // 512000 f (~2 MB)
    float* xp_part = (float*)(ws + 2097152);      // 8*64*4096 f (8 MB)

    k_qh<<<HK_, 64, 0, stream>>>(q, Wq, bq, qh);
    k_wk<<<F_, 256, 0, stream>>>(qh, Wk, bk, wk, ck);
    k_scores<<<1024, 256, 0, stream>>>(x, wk, ck, scores);
    k_softmax<<<B_ * H_, 256, 0, stream>>>(scores);
    k_xp<<<B_ * 8, 256, 0, stream>>>(x, scores, xp_part);
    k_tail<<<B_, 512, 0, stream>>>(xp_part, Wv, bv, Wo, bo, Wd, gamma, beta, out);
}

// Round 3
// 291.347 us; speedup vs baseline: 1.1505x; 1.0350x over previous
//
#include <hip/hip_runtime.h>
#include <cstddef>

#define B_ 64
#define T_ 1000
#define F_ 512
#define H_ 8
#define KD_ 32
#define HK_ 256   // H_*KD_
#define NC_ 16    // t-chunks: 8 of 63 + 8 of 62 = 1000

// ---------------- K1: qh[h,k] = sum_f q[f]*Wq[f,h,k] + bq[h,k] ----------------
__global__ __launch_bounds__(64) void k_qh(const float* __restrict__ q,
                                           const float* __restrict__ Wq,
                                           const float* __restrict__ bq,
                                           float* __restrict__ qh) {
    int hk = blockIdx.x;           // 0..255
    int lane = threadIdx.x;        // 0..63
    float s = 0.f;
    for (int f = lane; f < F_; f += 64) s += q[f] * Wq[(size_t)f * HK_ + hk];
    #pragma unroll
    for (int off = 32; off; off >>= 1) s += __shfl_down(s, off);
    if (lane == 0) qh[hk] = s + bq[hk];
}

// ---------------- K2: wk[f,h] = sum_k qh[h,k]*Wk[f,h,k]; ck[h] = qh[h,:].bk[h,:] ----------------
__global__ __launch_bounds__(256) void k_wk(const float* __restrict__ qh,
                                            const float* __restrict__ Wk,
                                            const float* __restrict__ bk,
                                            float* __restrict__ wk,
                                            float* __restrict__ ck) {
    int f = blockIdx.x;            // 0..511
    int tid = threadIdx.x;         // tid = h*32+k
    __shared__ float red[256];
    red[tid] = qh[tid] * Wk[(size_t)f * HK_ + tid];
    __syncthreads();
    #pragma unroll
    for (int off = 16; off; off >>= 1) {
        if ((tid & 31) < off) red[tid] += red[tid + off];
        __syncthreads();
    }
    if ((tid & 31) == 0) wk[f * H_ + (tid >> 5)] = red[tid];
    if (f == 0 && tid < H_) {
        float c = 0.f;
        for (int k = 0; k < KD_; k++) c += qh[tid * KD_ + k] * bk[tid * KD_ + k];
        ck[tid] = c;
    }
}

// ---------------- K3 (fused): per (b, t-chunk): scores -> local softmax -> weighted x partial ----------------
// Writes: part[c][b][h][f] (unnormalized, chunk-local max), ml[c][b][h][{m,l}]
__global__ __launch_bounds__(256) void k_fused(const float* __restrict__ x,
                                               const float* __restrict__ wk,
                                               const float* __restrict__ ck,
                                               float* __restrict__ part,
                                               float* __restrict__ ml) {
    int c = blockIdx.x & (NC_ - 1);
    int b = blockIdx.x >> 4;
    int nt = (c < 8) ? 63 : 62;
    int t0 = (c < 8) ? c * 63 : 504 + (c - 8) * 62;
    int tid = threadIdx.x;
    int lane = tid & 63, w = tid >> 6;    // 4 waves

    __shared__ float sp[H_][65];          // scores, then p=exp(s-m)

    // --- phase 1: scores for this chunk ---
    {
        int f0 = lane * 8;
        float wreg[8][8];                 // [i][h], h contiguous in wk
        #pragma unroll
        for (int i = 0; i < 8; i++)
            #pragma unroll
            for (int h = 0; h < H_; h++) wreg[i][h] = wk[(f0 + i) * H_ + h];
        float ckv = ck[lane >> 3];
        const float scale = 0.17677669529663687f;  // 1/sqrt(32)

        for (int tl = w; tl < nt; tl += 4) {
            const float4* xr = (const float4*)(x + ((size_t)(b * T_ + t0 + tl)) * F_ + f0);
            float4 a = xr[0], bb = xr[1];
            float xv[8] = {a.x, a.y, a.z, a.w, bb.x, bb.y, bb.z, bb.w};
            float acc[8];
            #pragma unroll
            for (int h = 0; h < H_; h++) acc[h] = 0.f;
            #pragma unroll
            for (int i = 0; i < 8; i++)
                #pragma unroll
                for (int h = 0; h < H_; h++) acc[h] += xv[i] * wreg[i][h];
            // stage 1: reduce over lane bits 3..5 (all 8 accs)
            #pragma unroll
            for (int h = 0; h < H_; h++) {
                acc[h] += __shfl_xor(acc[h], 8);
                acc[h] += __shfl_xor(acc[h], 16);
                acc[h] += __shfl_xor(acc[h], 32);
            }
            // stage 2: lane picks h = lane>>3, reduce over bits 0..2
            float v = acc[0];
            #pragma unroll
            for (int h = 1; h < H_; h++) v = ((lane >> 3) == h) ? acc[h] : v;
            v += __shfl_xor(v, 1);
            v += __shfl_xor(v, 2);
            v += __shfl_xor(v, 4);
            if ((lane & 7) == 0) sp[lane >> 3][tl] = (v + ckv) * scale;
        }
    }
    __syncthreads();

    // --- local softmax stats: per h (group of 32 threads) ---
    {
        int g = tid >> 5, j = tid & 31;
        float m = -1e30f;
        #pragma unroll
        for (int i = 0; i < 2; i++) { int t = j + 32 * i; if (t < nt) m = fmaxf(m, sp[g][t]); }
        #pragma unroll
        for (int off = 16; off; off >>= 1) m = fmaxf(m, __shfl_xor(m, off));
        float l = 0.f;
        float e0 = 0.f, e1 = 0.f;
        { int t = j;      if (t < nt) { e0 = __expf(sp[g][t] - m); l += e0; } }
        { int t = j + 32; if (t < nt) { e1 = __expf(sp[g][t] - m); l += e1; } }
        __syncthreads();   // everyone done reading sp as scores
        { int t = j;      if (t < nt) sp[g][t] = e0; }
        { int t = j + 32; if (t < nt) sp[g][t] = e1; }
        #pragma unroll
        for (int off = 16; off; off >>= 1) l += __shfl_xor(l, off);
        if (j == 0) {
            float* d = ml + ((size_t)(c * B_ + b) * H_ + g) * 2;
            d[0] = m; d[1] = l;
        }
    }
    __syncthreads();

    // --- phase 2: partial weighted sum over chunk; x re-read is L2/L3-hot ---
    {
        float acc[H_][2];
        #pragma unroll
        for (int h = 0; h < H_; h++) { acc[h][0] = 0.f; acc[h][1] = 0.f; }
        const float2* xb = (const float2*)(x + ((size_t)(b * T_ + t0)) * F_) + tid;
        for (int tt = 0; tt < nt; tt++) {
            float2 xv = xb[(size_t)tt * 256];
            #pragma unroll
            for (int h = 0; h < H_; h++) {
                float a = sp[h][tt];
                acc[h][0] += a * xv.x;
                acc[h][1] += a * xv.y;
            }
        }
        float2* dst = (float2*)(part + (size_t)(c * B_ + b) * (H_ * F_));
        #pragma unroll
        for (int h = 0; h < H_; h++)
            dst[h * (F_ / 2) + tid] = make_float2(acc[h][0], acc[h][1]);
    }
}

// ---------------- K4: combine chunks -> ctx -> pooled -> Wd -> LayerNorm, one block per b ----------------
__global__ __launch_bounds__(512) void k_tail(const float* __restrict__ part,
                                              const float* __restrict__ ml,
                                              const float* __restrict__ Wv,
                                              const float* __restrict__ bv,
                                              const float* __restrict__ Wo,
                                              const float* __restrict__ bo,
                                              const float* __restrict__ Wd,
                                              const float* __restrict__ gamma,
                                              const float* __restrict__ beta,
                                              float* __restrict__ out) {
    int b = blockIdx.x;
    int tid = threadIdx.x;
    __shared__ float coefs[NC_][H_];
    __shared__ float xs[H_ * F_];     // 16 KB, [h][f] = sum_t attn*x (normalized)
    __shared__ float ctx_s[HK_];
    __shared__ float pooled_s[F_];
    __shared__ float red[512];
    __shared__ float stat[2];

    if (tid < H_) {
        int h = tid;
        float M = -1e30f;
        #pragma unroll
        for (int c = 0; c < NC_; c++)
            M = fmaxf(M, ml[((size_t)(c * B_ + b) * H_ + h) * 2]);
        float L = 0.f;
        #pragma unroll
        for (int c = 0; c < NC_; c++) {
            const float* d = ml + ((size_t)(c * B_ + b) * H_ + h) * 2;
            L += __expf(d[0] - M) * d[1];
        }
        float invL = 1.0f / L;
        #pragma unroll
        for (int c = 0; c < NC_; c++) {
            const float* d = ml + ((size_t)(c * B_ + b) * H_ + h) * 2;
            coefs[c][h] = __expf(d[0] - M) * invL;
        }
    }
    __syncthreads();

    for (int i = tid; i < H_ * F_; i += 512) {
        int h = i >> 9;
        float s = 0.f;
        #pragma unroll
        for (int c = 0; c < NC_; c++)
            s += coefs[c][h] * part[(size_t)(c * B_ + b) * (H_ * F_) + i];
        xs[i] = s;
    }
    __syncthreads();

    // ctx[hk] = sum_f xs[h][f]*Wv[f*256+hk] + bv[hk]; split f over 2 halves
    {
        int hk = tid & 255;
        int half = tid >> 8;
        int h = hk >> 5;
        float s = 0.f;
        int fb = half * 256;
        for (int j = 0; j < 256; j++) {
            int f = fb + j;
            s += xs[h * F_ + f] * Wv[(size_t)f * HK_ + hk];
        }
        red[tid] = s;
        __syncthreads();
        if (tid < 256) ctx_s[tid] = red[tid] + red[tid + 256] + bv[tid];
    }
    __syncthreads();

    // pooled[f] = sum_hk ctx[hk]*Wo[hk*512+f] + bo[f]
    {
        float s = 0.f;
        for (int hk = 0; hk < HK_; hk++) s += ctx_s[hk] * Wo[(size_t)hk * F_ + tid];
        pooled_s[tid] = s + bo[tid];
    }
    __syncthreads();

    // o[f] = sum_g pooled[g]*Wd[g*512+f]
    float o = 0.f;
    for (int g = 0; g < F_; g++) o += pooled_s[g] * Wd[(size_t)g * F_ + tid];

    // LayerNorm over 512
    {
        float v1 = o, v2 = o * o;
        #pragma unroll
        for (int off = 32; off; off >>= 1) {
            v1 += __shfl_down(v1, off);
            v2 += __shfl_down(v2, off);
        }
        int lane = tid & 63, wid = tid >> 6;
        if (lane == 0) { red[wid] = v1; red[8 + wid] = v2; }
        __syncthreads();
        if (tid == 0) {
            float s1 = 0.f, s2 = 0.f;
            #pragma unroll
            for (int w = 0; w < 8; w++) { s1 += red[w]; s2 += red[8 + w]; }
            float mu = s1 * (1.0f / F_);
            float var = s2 * (1.0f / F_) - mu * mu;
            stat[0] = mu;
            stat[1] = rsqrtf(var + 1e-6f);
        }
        __syncthreads();
    }
    float mu = stat[0], rstd = stat[1];
    out[(size_t)b * F_ + tid] = (o - mu) * rstd * gamma[tid] + beta[tid];
}

extern "C" void kernel_launch(void* const* d_in, const int* in_sizes, int n_in,
                              void* d_out, int out_size, void* d_ws, size_t ws_size,
                              hipStream_t stream) {
    const float* x     = (const float*)d_in[0];
    const float* q     = (const float*)d_in[1];
    const float* Wq    = (const float*)d_in[2];
    const float* bq    = (const float*)d_in[3];
    const float* Wk    = (const float*)d_in[4];
    const float* bk    = (const float*)d_in[5];
    const float* Wv    = (const float*)d_in[6];
    const float* bv    = (const float*)d_in[7];
    const float* Wo    = (const float*)d_in[8];
    const float* bo    = (const float*)d_in[9];
    const float* Wd    = (const float*)d_in[10];
    const float* gamma = (const float*)d_in[11];
    const float* beta  = (const float*)d_in[12];
    float* out = (float*)d_out;

    char* ws = (char*)d_ws;
    float* qh   = (float*)(ws + 0);            // 256 f
    float* wk   = (float*)(ws + 4096);         // 4096 f
    float* ck   = (float*)(ws + 20480);        // 8 f
    float* ml   = (float*)(ws + 24576);        // 16*64*8*2 f (64 KB)
    float* part = (float*)(ws + 1048576);      // 16*64*4096 f (16 MB)

    k_qh<<<HK_, 64, 0, stream>>>(q, Wq, bq, qh);
    k_wk<<<F_, 256, 0, stream>>>(qh, Wk, bk, wk, ck);
    k_fused<<<B_ * NC_, 256, 0, stream>>>(x, wk, ck, part, ml);
    k_tail<<<B_, 512, 0, stream>>>(part, ml, Wv, bv, Wo, bo, Wd, gamma, beta, out);
}